// Round 3
// baseline (757.215 us; speedup 1.0000x reference)
//
#include <hip/hip_runtime.h>
#include <math.h>

// ---------------- problem constants ----------------
#define B_    8
#define H_    56
#define W_    56
#define HW_   3136
#define C0_   256
#define C1_   512
#define C2_   1024
#define DIN_  1794      // raw conv_w K (includes 2 coord cols, folded into epilogue)
#define KD_   1792      // descriptor K (GEMM K), 56 chunks of 32
#define KCP_  56        // phi K-chunks
#define DOUT_ 448
#define NCHP_ 28        // phi N-chunks (448/16)
#define NC_   3136      // centers
#define NCHD_ 196       // dist N-chunks (3136/16)
#define KCD_  14        // dist K-chunks (448/32)
#define DTS_  452       // LDS D-tile row stride (floats)
#define PCH_  28672     // phip chunk stride in shorts (in-place alias of desc pixels)

typedef __attribute__((ext_vector_type(8))) short bh8;
typedef __attribute__((ext_vector_type(4))) float f32x4;

__device__ __forceinline__ short f2bf(float f) {
  union { float f; unsigned u; } v; v.f = f;
  unsigned r = v.u + 0x7fffu + ((v.u >> 16) & 1u);
  return (short)(r >> 16);
}
__device__ __forceinline__ float bf2f(short s) {
  union { unsigned u; float f; } v; v.u = ((unsigned)(unsigned short)s) << 16;
  return v.f;
}

// ======== desc0: pool(p0) -> desc[:, 0:256], transposed, bf16 ========
__global__ __launch_bounds__(256) void desc0_kernel(const float* __restrict__ p0,
                                                    short* __restrict__ desc) {
  __shared__ float sv[64 * 57];
  const int c0 = blockIdx.x * 64, h = blockIdx.y, b = blockIdx.z;
  for (int item = threadIdx.x; item < 64 * 56; item += 256) {
    int x = item % 56, c = item / 56;
    const float* src = p0 + (((size_t)(b * C0_ + c0 + c)) * 56 + h) * 56 + x;
    float s = src[0];
    if (h > 0)  s += src[-56];
    if (h < 55) s += src[56];
    sv[c * 57 + x] = s;
  }
  __syncthreads();
  for (int item = threadIdx.x; item < 56 * 8; item += 256) {
    int g = item & 7, w = item >> 3;
    bh8 o;
#pragma unroll
    for (int j = 0; j < 8; ++j) {
      const float* s0 = sv + (g * 8 + j) * 57;
      float v = s0[w];
      if (w > 0)  v += s0[w - 1];
      if (w < 55) v += s0[w + 1];
      o[j] = f2bf(v * (1.0f / 9.0f));
    }
    size_t pid = (size_t)b * HW_ + h * 56 + w;
    *(bh8*)(desc + pid * KD_ + c0 + g * 8) = o;
  }
}

// ======== desc1: pool(p1)+bilinear x2 -> desc[:, 256:768] ========
__global__ __launch_bounds__(256) void desc1_kernel(const float* __restrict__ p1,
                                                    short* __restrict__ desc) {
  __shared__ float sv[2 * 64 * 29];
  const int c0 = blockIdx.x * 64, h = blockIdx.y, b = blockIdx.z;
  float sy = (h + 0.5f) * 0.5f - 0.5f;
  float fyf = floorf(sy);
  float fy = sy - fyf;
  int iy = (int)fyf;
  int pya = min(max(iy, 0), 27), pyb = min(max(iy + 1, 0), 27);
  for (int item = threadIdx.x; item < 64 * 2 * 28; item += 256) {
    int x = item % 28;
    int pr = (item / 28) & 1;
    int c = item / 56;
    int r = pr ? pyb : pya;
    const float* src = p1 + (((size_t)(b * C1_ + c0 + c)) * 28 + r) * 28 + x;
    float s = src[0];
    if (r > 0)  s += src[-28];
    if (r < 27) s += src[28];
    sv[pr * (64 * 29) + c * 29 + x] = s;
  }
  __syncthreads();
  for (int item = threadIdx.x; item < 56 * 8; item += 256) {
    int g = item & 7, w = item >> 3;
    float sx = (w + 0.5f) * 0.5f - 0.5f;
    float fxf = floorf(sx);
    float fx = sx - fxf;
    int ix = (int)fxf;
    int x0 = min(max(ix, 0), 27), x1 = min(max(ix + 1, 0), 27);
    bh8 o;
#pragma unroll
    for (int j = 0; j < 8; ++j) {
      const float* s0 = sv + (g * 8 + j) * 29;
      const float* s1 = s0 + 64 * 29;
      float p00 = s0[x0] + (x0 > 0 ? s0[x0 - 1] : 0.f) + (x0 < 27 ? s0[x0 + 1] : 0.f);
      float p01 = s0[x1] + (x1 > 0 ? s0[x1 - 1] : 0.f) + (x1 < 27 ? s0[x1 + 1] : 0.f);
      float p10 = s1[x0] + (x0 > 0 ? s1[x0 - 1] : 0.f) + (x0 < 27 ? s1[x0 + 1] : 0.f);
      float p11 = s1[x1] + (x1 > 0 ? s1[x1 - 1] : 0.f) + (x1 < 27 ? s1[x1 + 1] : 0.f);
      float top = p00 + fx * (p01 - p00);
      float bot = p10 + fx * (p11 - p10);
      o[j] = f2bf((top + fy * (bot - top)) * (1.0f / 9.0f));
    }
    size_t pid = (size_t)b * HW_ + h * 56 + w;
    *(bh8*)(desc + pid * KD_ + C0_ + c0 + g * 8) = o;
  }
}

// ======== desc2: pool(p2)+bilinear x4 -> desc[:, 768:1792] ========
__global__ __launch_bounds__(256) void desc2_kernel(const float* __restrict__ p2,
                                                    short* __restrict__ desc) {
  __shared__ float sv[2 * 64 * 15];
  const int c0 = blockIdx.x * 64, h = blockIdx.y, b = blockIdx.z;
  float sy = (h + 0.5f) * 0.25f - 0.5f;
  float fyf = floorf(sy);
  float fy = sy - fyf;
  int iy = (int)fyf;
  int pya = min(max(iy, 0), 13), pyb = min(max(iy + 1, 0), 13);
  for (int item = threadIdx.x; item < 64 * 2 * 14; item += 256) {
    int x = item % 14;
    int pr = (item / 14) & 1;
    int c = item / 28;
    int r = pr ? pyb : pya;
    const float* src = p2 + (((size_t)(b * C2_ + c0 + c)) * 14 + r) * 14 + x;
    float s = src[0];
    if (r > 0)  s += src[-14];
    if (r < 13) s += src[14];
    sv[pr * (64 * 15) + c * 15 + x] = s;
  }
  __syncthreads();
  for (int item = threadIdx.x; item < 56 * 8; item += 256) {
    int g = item & 7, w = item >> 3;
    float sx = (w + 0.5f) * 0.25f - 0.5f;
    float fxf = floorf(sx);
    float fx = sx - fxf;
    int ix = (int)fxf;
    int x0 = min(max(ix, 0), 13), x1 = min(max(ix + 1, 0), 13);
    bh8 o;
#pragma unroll
    for (int j = 0; j < 8; ++j) {
      const float* s0 = sv + (g * 8 + j) * 15;
      const float* s1 = s0 + 64 * 15;
      float p00 = s0[x0] + (x0 > 0 ? s0[x0 - 1] : 0.f) + (x0 < 13 ? s0[x0 + 1] : 0.f);
      float p01 = s0[x1] + (x1 > 0 ? s0[x1 - 1] : 0.f) + (x1 < 13 ? s0[x1 + 1] : 0.f);
      float p10 = s1[x0] + (x0 > 0 ? s1[x0 - 1] : 0.f) + (x0 < 13 ? s1[x0 + 1] : 0.f);
      float p11 = s1[x1] + (x1 > 0 ? s1[x1 - 1] : 0.f) + (x1 < 13 ? s1[x1 + 1] : 0.f);
      float top = p00 + fx * (p01 - p00);
      float bot = p10 + fx * (p11 - p10);
      o[j] = f2bf((top + fy * (bot - top)) * (1.0f / 9.0f));
    }
    size_t pid = (size_t)b * HW_ + h * 56 + w;
    *(bh8*)(desc + pid * KD_ + C0_ + C1_ + c0 + g * 8) = o;
  }
}

// ---------------- |c_j|^2 from bf16-rounded C ----------------
__global__ void cent2_kernel(const float* __restrict__ C, float* __restrict__ c2) {
  int j = blockIdx.x * blockDim.x + threadIdx.x;
  if (j >= NC_) return;
  float s = 0.f;
  for (int d = 0; d < DOUT_; ++d) {
    float v = bf2f(f2bf(C[(size_t)d * NC_ + j]));
    s = fmaf(v, v, s);
  }
  c2[j] = s;
}

// ---------------- pack C (K=448 x N=3136) into B-frag layout ----------------
__global__ void cpack_kernel(const float* __restrict__ C, short* __restrict__ Cpk) {
  int idx = blockIdx.x * 256 + threadIdx.x;       // NCHD_*KCD_*64 = 175616 exact
  int ln = idx & 63;
  int kc = (idx >> 6) % KCD_;
  int nc = idx / (KCD_ * 64);
  int n  = nc * 16 + (ln & 15);
  int k0 = kc * 32 + ((ln >> 4) << 3);
  bh8 o;
#pragma unroll
  for (int j = 0; j < 8; ++j) o[j] = f2bf(C[(size_t)(k0 + j) * NC_ + n]);
  *(bh8*)(Cpk + (size_t)idx * 8) = o;
}

// ---------------- pack W^T (K=1792 x N=448) into B-frag layout ----------------
__global__ void wpack_kernel(const float* __restrict__ W, short* __restrict__ Wpk) {
  int idx = blockIdx.x * 256 + threadIdx.x;       // NCHP_*KCP_*64 = 100352 exact
  int ln = idx & 63;
  int kc = (idx >> 6) % KCP_;
  int nc = idx / (KCP_ * 64);
  int n  = nc * 16 + (ln & 15);
  int k0 = kc * 32 + ((ln >> 4) << 3);
  bh8 o;
#pragma unroll
  for (int j = 0; j < 8; ++j) o[j] = f2bf(W[(size_t)n * DIN_ + k0 + j]);
  *(bh8*)(Wpk + (size_t)idx * 8) = o;
}

#define L7(X) X(0) X(1) X(2) X(3) X(4) X(5) X(6)

// ======== phi v2: explicit 2-deep software pipeline (named X/Y sets) ========
// Per kc the old loop serialized 9 global loads against their MFMA uses.
// Now: compute kc from set X while set Y (kc+1) is in flight; reissue X for
// kc+2 immediately after X's last use; sched_barrier(0) pins the issue point.
// Accumulation order per acc[rc][i] is kc-ascending — unchanged numerics.
__global__ __launch_bounds__(256) void phi_mfma(
    const short* __restrict__ desc, const short* __restrict__ Wpk,
    const float* __restrict__ cw, const float* __restrict__ cb,
    short* __restrict__ phip /* aliases desc */) {
  __shared__ __align__(16) float Dt[16 * DTS_];   // 28.9 KB
  const int wv = threadIdx.x >> 6, ln = threadIdx.x & 63;
  const int pix0 = blockIdx.x * 32;
  const short* aptr = desc + ((size_t)(pix0 + (ln & 15))) * KD_ + ((ln >> 4) << 3);
  const short* bbase = Wpk + (size_t)(wv * 7) * (KCP_ * 512) + ln * 8;

  f32x4 acc[2][7];
#pragma unroll
  for (int rc = 0; rc < 2; ++rc)
#pragma unroll
    for (int i = 0; i < 7; ++i) acc[rc][i] = (f32x4){0.f, 0.f, 0.f, 0.f};

#define WOFF(i, kc) ((size_t)(i) * (KCP_ * 512) + (size_t)(kc) * 512)
  // prime: X <- kc=0, Y <- kc=1
  bh8 xa0 = *(const bh8*)(aptr);
  bh8 xa1 = *(const bh8*)(aptr + 16 * KD_);
#define PX(i) bh8 xb##i = *(const bh8*)(bbase + WOFF(i, 0));
  L7(PX)
#undef PX
  bh8 ya0 = *(const bh8*)(aptr + 32);
  bh8 ya1 = *(const bh8*)(aptr + 16 * KD_ + 32);
#define PY(i) bh8 yb##i = *(const bh8*)(bbase + WOFF(i, 1));
  L7(PY)
#undef PY

  for (int it = 0; it < 28; ++it) {
    int kc2 = 2 * it + 2; if (kc2 >= 56) kc2 = 0;   // wrapped redundant load
    int kc3 = 2 * it + 3; if (kc3 >= 56) kc3 = 1;
    // ---- compute X (kc = 2*it) ----
#define CX(i) acc[0][i] = __builtin_amdgcn_mfma_f32_16x16x32_bf16(xa0, xb##i, acc[0][i], 0, 0, 0); \
              acc[1][i] = __builtin_amdgcn_mfma_f32_16x16x32_bf16(xa1, xb##i, acc[1][i], 0, 0, 0);
    L7(CX)
#undef CX
    // ---- reissue X <- kc+2 ----
    xa0 = *(const bh8*)(aptr + (size_t)kc2 * 32);
    xa1 = *(const bh8*)(aptr + 16 * KD_ + (size_t)kc2 * 32);
#define RX(i) xb##i = *(const bh8*)(bbase + WOFF(i, kc2));
    L7(RX)
#undef RX
    __builtin_amdgcn_sched_barrier(0);
    // ---- compute Y (kc = 2*it+1) ----
#define CY(i) acc[0][i] = __builtin_amdgcn_mfma_f32_16x16x32_bf16(ya0, yb##i, acc[0][i], 0, 0, 0); \
              acc[1][i] = __builtin_amdgcn_mfma_f32_16x16x32_bf16(ya1, yb##i, acc[1][i], 0, 0, 0);
    L7(CY)
#undef CY
    // ---- reissue Y <- kc+3 ----
    ya0 = *(const bh8*)(aptr + (size_t)kc3 * 32);
    ya1 = *(const bh8*)(aptr + 16 * KD_ + (size_t)kc3 * 32);
#define RY(i) yb##i = *(const bh8*)(bbase + WOFF(i, kc3));
    L7(RY)
#undef RY
    __builtin_amdgcn_sched_barrier(0);
  }
#undef WOFF

  for (int rc = 0; rc < 2; ++rc) {
    __syncthreads();   // rc=0: all desc reads done; rc=1: all rc=0 repack reads done
#pragma unroll
    for (int i = 0; i < 7; ++i) {
      int col = (wv * 7 + i) * 16 + (ln & 15);
      float bias = cb[col];
      float wx = cw[(size_t)col * DIN_ + 1792];
      float wy = cw[(size_t)col * DIN_ + 1793];
#pragma unroll
      for (int r = 0; r < 4; ++r) {
        int row = ((ln >> 4) << 2) + r;
        int pid = pix0 + rc * 16 + row;
        int hw = pid % HW_;
        int hh = hw / 56, ww = hw % 56;
        float xx = (float)hh * (2.0f / 55.0f) - 1.0f;
        float yy = (float)ww * (2.0f / 55.0f) - 1.0f;
        Dt[row * DTS_ + col] = acc[rc][i][r] + bias + wx * xx + wy * yy;
      }
    }
    __syncthreads();
    short* op = phip + (size_t)(blockIdx.x * 2 + rc) * PCH_;
    for (int item = threadIdx.x; item < KCD_ * 64; item += 256) {
      int kc = item >> 6, lp = item & 63;
      int m = lp & 15, k0 = kc * 32 + ((lp >> 4) << 3);
      bh8 o;
#pragma unroll
      for (int j = 0; j < 8; ++j) o[j] = f2bf(Dt[m * DTS_ + k0 + j]);
      *(bh8*)(op + (size_t)item * 8) = o;
    }
  }
}

// ======== dist v12: barrier-free streaming + explicit 1-chunk-ahead register ====
// ======== prefetch (named P/Q ping-pong sets pinned by sched_barrier) ===========
// v9 proved per-wave critical path = 28 serialized load->use latencies/iter
// (~17k cy). Here each N-chunk's 14 B-frags are issued one chunk ahead into
// named regs; sched_barrier(0) stops the scheduler sinking them back to the
// use site (the R2 failure mode: VGPR stayed 88). Math/order bit-identical v9.
__device__ __forceinline__ void insert3(float& t0, float& t1, float& t2, float v) {
  if (v < t2) {
    if (v < t1) {
      t2 = t1;
      if (v < t0) { t1 = t0; t0 = v; } else t1 = v;
    } else t2 = v;
  }
}
__device__ __forceinline__ void merge3(float& a0, float& a1, float& a2,
                                       float b0, float b1, float b2) {
  float lo0 = fminf(a0, b0), hi0 = fmaxf(a0, b0);
  float lo1 = fminf(a1, b1), hi1 = fmaxf(a1, b1);
  float lo2 = fminf(a2, b2);
  a0 = lo0;
  a1 = fminf(hi0, lo1);
  a2 = fminf(fmaxf(hi0, lo1), fminf(hi1, lo2));
}
__device__ __forceinline__ float sumsq8(bh8 a, float s) {
#pragma unroll
  for (int j = 0; j < 8; ++j) { float v = bf2f(a[j]); s = fmaf(v, v, s); }
  return s;
}

#define AFRAG_LIST(X) X(0) X(1) X(2) X(3) X(4) X(5) X(6) X(7) X(8) X(9) X(10) X(11) X(12) X(13)

__global__ __launch_bounds__(256, 3) void dist_part(
    const short* __restrict__ phip, const short* __restrict__ Cpk,
    const float* __restrict__ c2g, float* __restrict__ part) {
  const int wv = threadIdx.x >> 6, ln = threadIdx.x & 63;
  const int chunk = blockIdx.x * 2 + (wv >> 1);   // 16-pixel chunk
  const int half  = wv & 1;                       // which half of the center bank

  const short* ap = phip + (size_t)chunk * PCH_ + ln * 8;
#define LOADA(i) bh8 A##i = *(const bh8*)(ap + (i) * 512);
  AFRAG_LIST(LOADA)
#undef LOADA

  // f2 per pixel row (self-consistent with bf16 MFMA dot)
  float sum = 0.f;
#define SQ(i) sum = sumsq8(A##i, sum);
  AFRAG_LIST(SQ)
#undef SQ
  sum += __shfl_xor(sum, 16, 64);
  sum += __shfl_xor(sum, 32, 64);
  const int rb = (ln >> 4) << 2;
  float f2r0 = __shfl(sum, rb + 0, 64);
  float f2r1 = __shfl(sum, rb + 1, 64);
  float f2r2 = __shfl(sum, rb + 2, 64);
  float f2r3 = __shfl(sum, rb + 3, 64);

  float t00 = 1e30f, t01 = 1e30f, t02 = 1e30f;
  float t10 = 1e30f, t11 = 1e30f, t12 = 1e30f;
  float t20 = 1e30f, t21 = 1e30f, t22 = 1e30f;
  float t30 = 1e30f, t31 = 1e30f, t32 = 1e30f;

  // B stream for this half: 98 N-chunks of 16 centers, 7168 shorts each
  const short* cb = Cpk + ((size_t)half * (NCHD_ / 2)) * (KCD_ * 512) + ln * 8;
  const float* c2b = c2g + half * (NC_ / 2) + (ln & 15);

  // prime pipeline: P/Q <- nc=0, c2cur <- nc=0
#define PRP(i) bh8 P##i = *(const bh8*)(cb + (i) * 512);
  L7(PRP)
#undef PRP
#define PRQ(i) bh8 Q##i = *(const bh8*)(cb + (7 + (i)) * 512);
  L7(PRQ)
#undef PRQ
  float c2cur = c2b[0];

  for (int nc = 0; nc < NCHD_ / 2; ++nc) {   // 98 iterations, 1 N-chunk each
    int ncn = (nc < NCHD_ / 2 - 1) ? nc + 1 : nc;   // clamp: last prefetch redundant
    const short* bn = cb + (size_t)ncn * (KCD_ * 512);
    f32x4 acc = {0.f, 0.f, 0.f, 0.f};
    // ---- lo half: kc 0..6 from P ----
    acc = __builtin_amdgcn_mfma_f32_16x16x32_bf16(A0, P0, acc, 0, 0, 0);
    acc = __builtin_amdgcn_mfma_f32_16x16x32_bf16(A1, P1, acc, 0, 0, 0);
    acc = __builtin_amdgcn_mfma_f32_16x16x32_bf16(A2, P2, acc, 0, 0, 0);
    acc = __builtin_amdgcn_mfma_f32_16x16x32_bf16(A3, P3, acc, 0, 0, 0);
    acc = __builtin_amdgcn_mfma_f32_16x16x32_bf16(A4, P4, acc, 0, 0, 0);
    acc = __builtin_amdgcn_mfma_f32_16x16x32_bf16(A5, P5, acc, 0, 0, 0);
    acc = __builtin_amdgcn_mfma_f32_16x16x32_bf16(A6, P6, acc, 0, 0, 0);
    // ---- reissue P <- next chunk lo ----
#define RP(i) P##i = *(const bh8*)(bn + (i) * 512);
    L7(RP)
#undef RP
    __builtin_amdgcn_sched_barrier(0);
    // ---- hi half: kc 7..13 from Q ----
    acc = __builtin_amdgcn_mfma_f32_16x16x32_bf16(A7,  Q0, acc, 0, 0, 0);
    acc = __builtin_amdgcn_mfma_f32_16x16x32_bf16(A8,  Q1, acc, 0, 0, 0);
    acc = __builtin_amdgcn_mfma_f32_16x16x32_bf16(A9,  Q2, acc, 0, 0, 0);
    acc = __builtin_amdgcn_mfma_f32_16x16x32_bf16(A10, Q3, acc, 0, 0, 0);
    acc = __builtin_amdgcn_mfma_f32_16x16x32_bf16(A11, Q4, acc, 0, 0, 0);
    acc = __builtin_amdgcn_mfma_f32_16x16x32_bf16(A12, Q5, acc, 0, 0, 0);
    acc = __builtin_amdgcn_mfma_f32_16x16x32_bf16(A13, Q6, acc, 0, 0, 0);
    // ---- reissue Q <- next chunk hi, c2 prefetch ----
#define RQ(i) Q##i = *(const bh8*)(bn + (7 + (i)) * 512);
    L7(RQ)
#undef RQ
    float c2n = c2b[(size_t)ncn * 16];
    __builtin_amdgcn_sched_barrier(0);
    // ---- distances + top-3 (order identical to v9) ----
    insert3(t00, t01, t02, f2r0 + c2cur - 2.0f * acc[0]);
    insert3(t10, t11, t12, f2r1 + c2cur - 2.0f * acc[1]);
    insert3(t20, t21, t22, f2r2 + c2cur - 2.0f * acc[2]);
    insert3(t30, t31, t32, f2r3 + c2cur - 2.0f * acc[3]);
    c2cur = c2n;
  }

  // merge the 16 column-lanes (same pixel rows, different centers) — shfl only
#pragma unroll
  for (int m = 1; m <= 8; m <<= 1) {
    float b0, b1, b2;
    b0 = __shfl_xor(t00, m, 64); b1 = __shfl_xor(t01, m, 64); b2 = __shfl_xor(t02, m, 64);
    merge3(t00, t01, t02, b0, b1, b2);
    b0 = __shfl_xor(t10, m, 64); b1 = __shfl_xor(t11, m, 64); b2 = __shfl_xor(t12, m, 64);
    merge3(t10, t11, t12, b0, b1, b2);
    b0 = __shfl_xor(t20, m, 64); b1 = __shfl_xor(t21, m, 64); b2 = __shfl_xor(t22, m, 64);
    merge3(t20, t21, t22, b0, b1, b2);
    b0 = __shfl_xor(t30, m, 64); b1 = __shfl_xor(t31, m, 64); b2 = __shfl_xor(t32, m, 64);
    merge3(t30, t31, t32, b0, b1, b2);
  }

  if ((ln & 15) == 0) {
    float* q = part + ((size_t)(chunk * 16 + rb)) * 8 + half * 4;
    q[0] = t00; q[1] = t01; q[2] = t02;
    q[8] = t10; q[9] = t11; q[10] = t12;
    q[16] = t20; q[17] = t21; q[18] = t22;
    q[24] = t30; q[25] = t31; q[26] = t32;
  }
}

// ======== merge: combine 2 partial triples per pixel, softmin score ========
__global__ __launch_bounds__(256) void merge_kernel(const float* __restrict__ part,
                                                    float* __restrict__ out) {
  int p = blockIdx.x * 256 + threadIdx.x;   // 25088 exact
  const float* q = part + (size_t)p * 8;
  float a0 = q[0], a1 = q[1], a2 = q[2];
  merge3(a0, a1, a2, q[4], q[5], q[6]);
  float d0 = sqrtf(fmaxf(a0, 0.f));
  float d1 = sqrtf(fmaxf(a1, 0.f));
  float d2 = sqrtf(fmaxf(a2, 0.f));
  float s0 = 1.0f / (1.0f + expf(d0 - d1) + expf(d0 - d2));
  out[p] = s0 * d0;
}

// ---------------- launch ----------------
extern "C" void kernel_launch(void* const* d_in, const int* in_sizes, int n_in,
                              void* d_out, int out_size, void* d_ws, size_t ws_size,
                              hipStream_t stream) {
  const float* p0 = (const float*)d_in[0];
  const float* p1 = (const float*)d_in[1];
  const float* p2 = (const float*)d_in[2];
  const float* cw = (const float*)d_in[3];
  const float* cb = (const float*)d_in[4];
  const float* C  = (const float*)d_in[5];
  float* out = (float*)d_out;

  short* desc = (short*)d_ws;                                   // 44,957,696 shorts
  short* Cpk  = desc + (size_t)25088 * KD_;                     //  1,404,928 shorts
  short* Wpk  = Cpk + (size_t)NCHD_ * KCD_ * 512;               //    802,816 shorts
  float* c2   = (float*)(Wpk + (size_t)NCHP_ * KCP_ * 512);     //      3,136 floats
  float* part = c2 + NC_;                                       //    200,704 floats (~0.8 MB)

  desc0_kernel<<<dim3(4, 56, 8),  256, 0, stream>>>(p0, desc);
  desc1_kernel<<<dim3(8, 56, 8),  256, 0, stream>>>(p1, desc);
  desc2_kernel<<<dim3(16, 56, 8), 256, 0, stream>>>(p2, desc);
  cent2_kernel<<<(NC_ + 255) / 256, 256, 0, stream>>>(C, c2);
  cpack_kernel<<<NCHD_ * KCD_ * 64 / 256, 256, 0, stream>>>(C, Cpk);
  wpack_kernel<<<NCHP_ * KCP_ * 64 / 256, 256, 0, stream>>>(cw, Wpk);
  phi_mfma<<<25088 / 32, 256, 0, stream>>>(desc, Wpk, cw, cb, desc);
  dist_part<<<25088 / 32, 256, 0, stream>>>(desc, Cpk, c2, part);
  merge_kernel<<<25088 / 256, 256, 0, stream>>>(part, out);
}

// Round 4
// 687.004 us; speedup vs baseline: 1.1022x; 1.1022x over previous
//
#include <hip/hip_runtime.h>
#include <math.h>

// ---------------- problem constants ----------------
#define B_    8
#define H_    56
#define W_    56
#define HW_   3136
#define C0_   256
#define C1_   512
#define C2_   1024
#define DIN_  1794      // raw conv_w K (includes 2 coord cols, folded into epilogue)
#define KD_   1792      // descriptor K (GEMM K), 56 chunks of 32
#define KCP_  56        // phi K-chunks
#define DOUT_ 448
#define NCHP_ 28        // phi N-chunks (448/16)
#define NC_   3136      // centers
#define NCHD_ 196       // dist N-chunks (3136/16)
#define KCD_  14        // dist K-chunks (448/32)
#define DTS_  452       // LDS D-tile row stride (floats)
#define PCH_  28672     // phip chunk stride in shorts (in-place alias of desc pixels)

typedef __attribute__((ext_vector_type(8))) short bh8;
typedef __attribute__((ext_vector_type(4))) float f32x4;

__device__ __forceinline__ short f2bf(float f) {
  union { float f; unsigned u; } v; v.f = f;
  unsigned r = v.u + 0x7fffu + ((v.u >> 16) & 1u);
  return (short)(r >> 16);
}
__device__ __forceinline__ float bf2f(short s) {
  union { unsigned u; float f; } v; v.u = ((unsigned)(unsigned short)s) << 16;
  return v.f;
}

// ======== desc0: pool(p0) -> desc[:, 0:256], transposed, bf16 ========
__global__ __launch_bounds__(256) void desc0_kernel(const float* __restrict__ p0,
                                                    short* __restrict__ desc) {
  __shared__ float sv[64 * 57];
  const int c0 = blockIdx.x * 64, h = blockIdx.y, b = blockIdx.z;
  for (int item = threadIdx.x; item < 64 * 56; item += 256) {
    int x = item % 56, c = item / 56;
    const float* src = p0 + (((size_t)(b * C0_ + c0 + c)) * 56 + h) * 56 + x;
    float s = src[0];
    if (h > 0)  s += src[-56];
    if (h < 55) s += src[56];
    sv[c * 57 + x] = s;
  }
  __syncthreads();
  for (int item = threadIdx.x; item < 56 * 8; item += 256) {
    int g = item & 7, w = item >> 3;
    bh8 o;
#pragma unroll
    for (int j = 0; j < 8; ++j) {
      const float* s0 = sv + (g * 8 + j) * 57;
      float v = s0[w];
      if (w > 0)  v += s0[w - 1];
      if (w < 55) v += s0[w + 1];
      o[j] = f2bf(v * (1.0f / 9.0f));
    }
    size_t pid = (size_t)b * HW_ + h * 56 + w;
    *(bh8*)(desc + pid * KD_ + c0 + g * 8) = o;
  }
}

// ======== desc1: pool(p1)+bilinear x2 -> desc[:, 256:768] ========
__global__ __launch_bounds__(256) void desc1_kernel(const float* __restrict__ p1,
                                                    short* __restrict__ desc) {
  __shared__ float sv[2 * 64 * 29];
  const int c0 = blockIdx.x * 64, h = blockIdx.y, b = blockIdx.z;
  float sy = (h + 0.5f) * 0.5f - 0.5f;
  float fyf = floorf(sy);
  float fy = sy - fyf;
  int iy = (int)fyf;
  int pya = min(max(iy, 0), 27), pyb = min(max(iy + 1, 0), 27);
  for (int item = threadIdx.x; item < 64 * 2 * 28; item += 256) {
    int x = item % 28;
    int pr = (item / 28) & 1;
    int c = item / 56;
    int r = pr ? pyb : pya;
    const float* src = p1 + (((size_t)(b * C1_ + c0 + c)) * 28 + r) * 28 + x;
    float s = src[0];
    if (r > 0)  s += src[-28];
    if (r < 27) s += src[28];
    sv[pr * (64 * 29) + c * 29 + x] = s;
  }
  __syncthreads();
  for (int item = threadIdx.x; item < 56 * 8; item += 256) {
    int g = item & 7, w = item >> 3;
    float sx = (w + 0.5f) * 0.5f - 0.5f;
    float fxf = floorf(sx);
    float fx = sx - fxf;
    int ix = (int)fxf;
    int x0 = min(max(ix, 0), 27), x1 = min(max(ix + 1, 0), 27);
    bh8 o;
#pragma unroll
    for (int j = 0; j < 8; ++j) {
      const float* s0 = sv + (g * 8 + j) * 29;
      const float* s1 = s0 + 64 * 29;
      float p00 = s0[x0] + (x0 > 0 ? s0[x0 - 1] : 0.f) + (x0 < 27 ? s0[x0 + 1] : 0.f);
      float p01 = s0[x1] + (x1 > 0 ? s0[x1 - 1] : 0.f) + (x1 < 27 ? s0[x1 + 1] : 0.f);
      float p10 = s1[x0] + (x0 > 0 ? s1[x0 - 1] : 0.f) + (x0 < 27 ? s1[x0 + 1] : 0.f);
      float p11 = s1[x1] + (x1 > 0 ? s1[x1 - 1] : 0.f) + (x1 < 27 ? s1[x1 + 1] : 0.f);
      float top = p00 + fx * (p01 - p00);
      float bot = p10 + fx * (p11 - p10);
      o[j] = f2bf((top + fy * (bot - top)) * (1.0f / 9.0f));
    }
    size_t pid = (size_t)b * HW_ + h * 56 + w;
    *(bh8*)(desc + pid * KD_ + C0_ + c0 + g * 8) = o;
  }
}

// ======== desc2: pool(p2)+bilinear x4 -> desc[:, 768:1792] ========
__global__ __launch_bounds__(256) void desc2_kernel(const float* __restrict__ p2,
                                                    short* __restrict__ desc) {
  __shared__ float sv[2 * 64 * 15];
  const int c0 = blockIdx.x * 64, h = blockIdx.y, b = blockIdx.z;
  float sy = (h + 0.5f) * 0.25f - 0.5f;
  float fyf = floorf(sy);
  float fy = sy - fyf;
  int iy = (int)fyf;
  int pya = min(max(iy, 0), 13), pyb = min(max(iy + 1, 0), 13);
  for (int item = threadIdx.x; item < 64 * 2 * 14; item += 256) {
    int x = item % 14;
    int pr = (item / 14) & 1;
    int c = item / 28;
    int r = pr ? pyb : pya;
    const float* src = p2 + (((size_t)(b * C2_ + c0 + c)) * 14 + r) * 14 + x;
    float s = src[0];
    if (r > 0)  s += src[-14];
    if (r < 13) s += src[14];
    sv[pr * (64 * 15) + c * 15 + x] = s;
  }
  __syncthreads();
  for (int item = threadIdx.x; item < 56 * 8; item += 256) {
    int g = item & 7, w = item >> 3;
    float sx = (w + 0.5f) * 0.25f - 0.5f;
    float fxf = floorf(sx);
    float fx = sx - fxf;
    int ix = (int)fxf;
    int x0 = min(max(ix, 0), 13), x1 = min(max(ix + 1, 0), 13);
    bh8 o;
#pragma unroll
    for (int j = 0; j < 8; ++j) {
      const float* s0 = sv + (g * 8 + j) * 15;
      const float* s1 = s0 + 64 * 15;
      float p00 = s0[x0] + (x0 > 0 ? s0[x0 - 1] : 0.f) + (x0 < 13 ? s0[x0 + 1] : 0.f);
      float p01 = s0[x1] + (x1 > 0 ? s0[x1 - 1] : 0.f) + (x1 < 13 ? s0[x1 + 1] : 0.f);
      float p10 = s1[x0] + (x0 > 0 ? s1[x0 - 1] : 0.f) + (x0 < 13 ? s1[x0 + 1] : 0.f);
      float p11 = s1[x1] + (x1 > 0 ? s1[x1 - 1] : 0.f) + (x1 < 13 ? s1[x1 + 1] : 0.f);
      float top = p00 + fx * (p01 - p00);
      float bot = p10 + fx * (p11 - p10);
      o[j] = f2bf((top + fy * (bot - top)) * (1.0f / 9.0f));
    }
    size_t pid = (size_t)b * HW_ + h * 56 + w;
    *(bh8*)(desc + pid * KD_ + C0_ + C1_ + c0 + g * 8) = o;
  }
}

// ---------------- |c_j|^2 from bf16-rounded C ----------------
__global__ void cent2_kernel(const float* __restrict__ C, float* __restrict__ c2) {
  int j = blockIdx.x * blockDim.x + threadIdx.x;
  if (j >= NC_) return;
  float s = 0.f;
  for (int d = 0; d < DOUT_; ++d) {
    float v = bf2f(f2bf(C[(size_t)d * NC_ + j]));
    s = fmaf(v, v, s);
  }
  c2[j] = s;
}

// ---------------- pack C (K=448 x N=3136) into B-frag layout ----------------
__global__ void cpack_kernel(const float* __restrict__ C, short* __restrict__ Cpk) {
  int idx = blockIdx.x * 256 + threadIdx.x;       // NCHD_*KCD_*64 = 175616 exact
  int ln = idx & 63;
  int kc = (idx >> 6) % KCD_;
  int nc = idx / (KCD_ * 64);
  int n  = nc * 16 + (ln & 15);
  int k0 = kc * 32 + ((ln >> 4) << 3);
  bh8 o;
#pragma unroll
  for (int j = 0; j < 8; ++j) o[j] = f2bf(C[(size_t)(k0 + j) * NC_ + n]);
  *(bh8*)(Cpk + (size_t)idx * 8) = o;
}

// ---------------- pack W^T (K=1792 x N=448) into B-frag layout ----------------
__global__ void wpack_kernel(const float* __restrict__ W, short* __restrict__ Wpk) {
  int idx = blockIdx.x * 256 + threadIdx.x;       // NCHP_*KCP_*64 = 100352 exact
  int ln = idx & 63;
  int kc = (idx >> 6) % KCP_;
  int nc = idx / (KCP_ * 64);
  int n  = nc * 16 + (ln & 15);
  int k0 = kc * 32 + ((ln >> 4) << 3);
  bh8 o;
#pragma unroll
  for (int j = 0; j < 8; ++j) o[j] = f2bf(W[(size_t)n * DIN_ + k0 + j]);
  *(bh8*)(Wpk + (size_t)idx * 8) = o;
}

// ======== phi: A-frags direct from desc; bias+coords fused; in-place phipack ========
__global__ __launch_bounds__(256) void phi_mfma(
    const short* __restrict__ desc, const short* __restrict__ Wpk,
    const float* __restrict__ cw, const float* __restrict__ cb,
    short* __restrict__ phip /* aliases desc */) {
  __shared__ __align__(16) float Dt[16 * DTS_];   // 28.9 KB
  const int wv = threadIdx.x >> 6, ln = threadIdx.x & 63;
  const int pix0 = blockIdx.x * 32;
  const short* aptr = desc + ((size_t)(pix0 + (ln & 15))) * KD_ + ((ln >> 4) << 3);

  f32x4 acc[2][7];
#pragma unroll
  for (int rc = 0; rc < 2; ++rc)
#pragma unroll
    for (int i = 0; i < 7; ++i) acc[rc][i] = (f32x4){0.f, 0.f, 0.f, 0.f};

  const short* bbase = Wpk + (size_t)(wv * 7) * (KCP_ * 512) + ln * 8;
  for (int kc = 0; kc < KCP_; ++kc) {
    bh8 a0 = *(const bh8*)(aptr + kc * 32);
    bh8 a1 = *(const bh8*)(aptr + 16 * KD_ + kc * 32);
    const short* bp = bbase + kc * 512;
#pragma unroll
    for (int i = 0; i < 7; ++i) {
      bh8 bfr = *(const bh8*)(bp + (size_t)i * (KCP_ * 512));
      acc[0][i] = __builtin_amdgcn_mfma_f32_16x16x32_bf16(a0, bfr, acc[0][i], 0, 0, 0);
      acc[1][i] = __builtin_amdgcn_mfma_f32_16x16x32_bf16(a1, bfr, acc[1][i], 0, 0, 0);
    }
  }

  for (int rc = 0; rc < 2; ++rc) {
    __syncthreads();   // rc=0: all desc reads done; rc=1: all rc=0 repack reads done
#pragma unroll
    for (int i = 0; i < 7; ++i) {
      int col = (wv * 7 + i) * 16 + (ln & 15);
      float bias = cb[col];
      float wx = cw[(size_t)col * DIN_ + 1792];
      float wy = cw[(size_t)col * DIN_ + 1793];
#pragma unroll
      for (int r = 0; r < 4; ++r) {
        int row = ((ln >> 4) << 2) + r;
        int pid = pix0 + rc * 16 + row;
        int hw = pid % HW_;
        int hh = hw / 56, ww = hw % 56;
        float xx = (float)hh * (2.0f / 55.0f) - 1.0f;
        float yy = (float)ww * (2.0f / 55.0f) - 1.0f;
        Dt[row * DTS_ + col] = acc[rc][i][r] + bias + wx * xx + wy * yy;
      }
    }
    __syncthreads();
    short* op = phip + (size_t)(blockIdx.x * 2 + rc) * PCH_;
    for (int item = threadIdx.x; item < KCD_ * 64; item += 256) {
      int kc = item >> 6, lp = item & 63;
      int m = lp & 15, k0 = kc * 32 + ((lp >> 4) << 3);
      bh8 o;
#pragma unroll
      for (int j = 0; j < 8; ++j) o[j] = f2bf(Dt[m * DTS_ + k0 + j]);
      *(bh8*)(op + (size_t)item * 8) = o;
    }
  }
}

// ======== dist v13: A-frags in LDS (kills register pressure / scratch spills), ====
// ======== B-frags group-loaded into the freed registers, quarter-bank per wave ====
// R3 diagnosis: WRITE_SIZE 98-103 MB = scratch spill traffic. 14 A-frags (56 VGPR)
// + prefetch state never fit; every MFMA operand was a scratch reload at memory
// latency. Fix: A lives in LDS (reused 49x, ds_read ~12cy); per N-chunk the 14 B
// loads go into named regs as ONE cluster -> one global latency per iteration.
// Live set ~90 VGPR < 128 budget at (256,4): no spills.
// Block = 4 waves, one 16-pixel chunk; wave wv sweeps quarter wv of the center
// bank (49 N-chunks). Quarter partials are exact top-3; combined in-block so the
// part buffer / merge_kernel stay identical to the passing version.
__device__ __forceinline__ void insert3(float& t0, float& t1, float& t2, float v) {
  if (v < t2) {
    if (v < t1) {
      t2 = t1;
      if (v < t0) { t1 = t0; t0 = v; } else t1 = v;
    } else t2 = v;
  }
}
__device__ __forceinline__ void merge3(float& a0, float& a1, float& a2,
                                       float b0, float b1, float b2) {
  float lo0 = fminf(a0, b0), hi0 = fmaxf(a0, b0);
  float lo1 = fminf(a1, b1), hi1 = fmaxf(a1, b1);
  float lo2 = fminf(a2, b2);
  a0 = lo0;
  a1 = fminf(hi0, lo1);
  a2 = fminf(fmaxf(hi0, lo1), fminf(hi1, lo2));
}
__device__ __forceinline__ float sumsq8(bh8 a, float s) {
#pragma unroll
  for (int j = 0; j < 8; ++j) { float v = bf2f(a[j]); s = fmaf(v, v, s); }
  return s;
}

#define KLIST(X) X(0) X(1) X(2) X(3) X(4) X(5) X(6) X(7) X(8) X(9) X(10) X(11) X(12) X(13)

__global__ __launch_bounds__(256, 4) void dist_part(
    const short* __restrict__ phip, const short* __restrict__ Cpk,
    const float* __restrict__ c2g, float* __restrict__ part) {
  __shared__ __align__(16) short Asl[14336];   // 28 KB: this block's A-chunk
  __shared__ float tri[4][16][4];              // quarter partial triples
  const int wv = threadIdx.x >> 6, ln = threadIdx.x & 63;
  const int chunk = blockIdx.x;                // 16-pixel chunk

  // stage A-chunk (28672 B) linearly into LDS via async DMA; wave wv owns 7168 B
  {
    const short* g_ = phip + (size_t)chunk * PCH_ + wv * 3584 + ln * 8;
    short* l_ = Asl + wv * 3584;
#pragma unroll
    for (int j = 0; j < 7; ++j)
      __builtin_amdgcn_global_load_lds(
          (const __attribute__((address_space(1))) unsigned int*)(g_ + j * 512),
          (__attribute__((address_space(3))) unsigned int*)(l_ + j * 512),
          16, 0, 0);
  }
  __syncthreads();   // drains vmcnt(0): A staged

  const short* alds = Asl + ln * 8;   // lane's A-frag kc at + kc*512

  // f2 per pixel row (self-consistent with bf16 MFMA dot; same order as before)
  float sum = 0.f;
#pragma unroll
  for (int i = 0; i < 14; ++i) sum = sumsq8(*(const bh8*)(alds + i * 512), sum);
  sum += __shfl_xor(sum, 16, 64);
  sum += __shfl_xor(sum, 32, 64);
  const int rb = (ln >> 4) << 2;
  float f2r0 = __shfl(sum, rb + 0, 64);
  float f2r1 = __shfl(sum, rb + 1, 64);
  float f2r2 = __shfl(sum, rb + 2, 64);
  float f2r3 = __shfl(sum, rb + 3, 64);

  float t00 = 1e30f, t01 = 1e30f, t02 = 1e30f;
  float t10 = 1e30f, t11 = 1e30f, t12 = 1e30f;
  float t20 = 1e30f, t21 = 1e30f, t22 = 1e30f;
  float t30 = 1e30f, t31 = 1e30f, t32 = 1e30f;

  // wave wv sweeps quarter wv: N-chunks [wv*49, wv*49+49)
  const short* cb = Cpk + (size_t)wv * 49 * (KCD_ * 512) + ln * 8;
  const float* c2b = c2g + wv * 49 * 16 + (ln & 15);

  for (int nc = 0; nc < 49; ++nc) {
    const short* bp = cb + (size_t)nc * (KCD_ * 512);
    // 14 independent global loads -> named regs (one latency for the group)
#define LB(kc) bh8 B##kc = *(const bh8*)(bp + (kc) * 512);
    KLIST(LB)
#undef LB
    f32x4 acc = {0.f, 0.f, 0.f, 0.f};
    // A from LDS just-in-time (ds_read overlaps the B vmcnt wait)
#define MF(kc) acc = __builtin_amdgcn_mfma_f32_16x16x32_bf16( \
        *(const bh8*)(alds + (kc) * 512), B##kc, acc, 0, 0, 0);
    KLIST(MF)
#undef MF
    float c2v = c2b[nc * 16];
    insert3(t00, t01, t02, f2r0 + c2v - 2.0f * acc[0]);
    insert3(t10, t11, t12, f2r1 + c2v - 2.0f * acc[1]);
    insert3(t20, t21, t22, f2r2 + c2v - 2.0f * acc[2]);
    insert3(t30, t31, t32, f2r3 + c2v - 2.0f * acc[3]);
  }

  // merge the 16 column-lanes (same pixel rows, different centers) — shfl only
#pragma unroll
  for (int m = 1; m <= 8; m <<= 1) {
    float b0, b1, b2;
    b0 = __shfl_xor(t00, m, 64); b1 = __shfl_xor(t01, m, 64); b2 = __shfl_xor(t02, m, 64);
    merge3(t00, t01, t02, b0, b1, b2);
    b0 = __shfl_xor(t10, m, 64); b1 = __shfl_xor(t11, m, 64); b2 = __shfl_xor(t12, m, 64);
    merge3(t10, t11, t12, b0, b1, b2);
    b0 = __shfl_xor(t20, m, 64); b1 = __shfl_xor(t21, m, 64); b2 = __shfl_xor(t22, m, 64);
    merge3(t20, t21, t22, b0, b1, b2);
    b0 = __shfl_xor(t30, m, 64); b1 = __shfl_xor(t31, m, 64); b2 = __shfl_xor(t32, m, 64);
    merge3(t30, t31, t32, b0, b1, b2);
  }

  // stash quarter partials; combine quarters {0,1}->half0, {2,3}->half1 in-block
  if ((ln & 15) == 0) {
    tri[wv][rb + 0][0] = t00; tri[wv][rb + 0][1] = t01; tri[wv][rb + 0][2] = t02;
    tri[wv][rb + 1][0] = t10; tri[wv][rb + 1][1] = t11; tri[wv][rb + 1][2] = t12;
    tri[wv][rb + 2][0] = t20; tri[wv][rb + 2][1] = t21; tri[wv][rb + 2][2] = t22;
    tri[wv][rb + 3][0] = t30; tri[wv][rb + 3][1] = t31; tri[wv][rb + 3][2] = t32;
  }
  __syncthreads();
  if (threadIdx.x < 32) {
    int p = threadIdx.x & 15, hh = threadIdx.x >> 4;
    float a0 = tri[2 * hh][p][0], a1 = tri[2 * hh][p][1], a2 = tri[2 * hh][p][2];
    merge3(a0, a1, a2, tri[2 * hh + 1][p][0], tri[2 * hh + 1][p][1], tri[2 * hh + 1][p][2]);
    float* o = part + ((size_t)(chunk * 16 + p)) * 8 + hh * 4;
    o[0] = a0; o[1] = a1; o[2] = a2;
  }
}

// ======== merge: combine 2 partial triples per pixel, softmin score ========
__global__ __launch_bounds__(256) void merge_kernel(const float* __restrict__ part,
                                                    float* __restrict__ out) {
  int p = blockIdx.x * 256 + threadIdx.x;   // 25088 exact
  const float* q = part + (size_t)p * 8;
  float a0 = q[0], a1 = q[1], a2 = q[2];
  merge3(a0, a1, a2, q[4], q[5], q[6]);
  float d0 = sqrtf(fmaxf(a0, 0.f));
  float d1 = sqrtf(fmaxf(a1, 0.f));
  float d2 = sqrtf(fmaxf(a2, 0.f));
  float s0 = 1.0f / (1.0f + expf(d0 - d1) + expf(d0 - d2));
  out[p] = s0 * d0;
}

// ---------------- launch ----------------
extern "C" void kernel_launch(void* const* d_in, const int* in_sizes, int n_in,
                              void* d_out, int out_size, void* d_ws, size_t ws_size,
                              hipStream_t stream) {
  const float* p0 = (const float*)d_in[0];
  const float* p1 = (const float*)d_in[1];
  const float* p2 = (const float*)d_in[2];
  const float* cw = (const float*)d_in[3];
  const float* cb = (const float*)d_in[4];
  const float* C  = (const float*)d_in[5];
  float* out = (float*)d_out;

  short* desc = (short*)d_ws;                                   // 44,957,696 shorts
  short* Cpk  = desc + (size_t)25088 * KD_;                     //  1,404,928 shorts
  short* Wpk  = Cpk + (size_t)NCHD_ * KCD_ * 512;               //    802,816 shorts
  float* c2   = (float*)(Wpk + (size_t)NCHP_ * KCP_ * 512);     //      3,136 floats
  float* part = c2 + NC_;                                       //    200,704 floats (~0.8 MB)

  desc0_kernel<<<dim3(4, 56, 8),  256, 0, stream>>>(p0, desc);
  desc1_kernel<<<dim3(8, 56, 8),  256, 0, stream>>>(p1, desc);
  desc2_kernel<<<dim3(16, 56, 8), 256, 0, stream>>>(p2, desc);
  cent2_kernel<<<(NC_ + 255) / 256, 256, 0, stream>>>(C, c2);
  cpack_kernel<<<NCHD_ * KCD_ * 64 / 256, 256, 0, stream>>>(C, Cpk);
  wpack_kernel<<<NCHP_ * KCP_ * 64 / 256, 256, 0, stream>>>(cw, Wpk);
  phi_mfma<<<25088 / 32, 256, 0, stream>>>(desc, Wpk, cw, cb, desc);
  dist_part<<<1568, 256, 0, stream>>>(desc, Cpk, c2, part);
  merge_kernel<<<25088 / 256, 256, 0, stream>>>(part, out);
}